// Round 7
// baseline (569.781 us; speedup 1.0000x reference)
//
#include <hip/hip_runtime.h>

// out[n,:] = ci[n] * sum_{e: dst[e]==n} sigmoid(<review_feat[e,:], ps_w>) * cj[src[e]] * weight[src[e],:]
//
// Round-6 lesson: kD ILP was neutral; residual ~250us must be kC, whose
// dependent chain (stream load -> atomic return -> scattered write) gates the
// 819MB review stream (vmcnt is in-order: waiting on the atomic drains the
// next prefetched stream load). Round 7 splits kC:
//   kC1: PURE stream: review_feat -> scale[e].  4 independent 1KB loads in
//        flight per wave (16 consecutive edges/iter), contiguous scale write.
//   kC2: scatter: 1 thread/edge, coalesced src/dst/scale, fold cj*ci, cursor
//        atomic, 8B pair write. Latency-bound but massively wave-parallel.
// Everything else identical to round 6 for clean A/B.

#define TILE_LOG 12
#define TILE (1 << TILE_LOG)   // 4096 elems per scan tile

// ---------------- kZ: zero the degree array ----------------
__global__ __launch_bounds__(256) void kZ_zero(unsigned* __restrict__ p, int n)
{
    const int i = blockIdx.x * 256 + threadIdx.x;
    if (i < n) p[i] = 0u;
}

// ---------------- kA: degree histogram ----------------
__global__ __launch_bounds__(256) void kA_hist(
    const int* __restrict__ dst, unsigned* __restrict__ deg, int E)
{
    const long long stride = (long long)gridDim.x * blockDim.x;
    for (long long e = (long long)blockIdx.x * blockDim.x + threadIdx.x; e < E; e += stride)
        atomicAdd(&deg[dst[e]], 1u);
}

// ---------------- kB1: per-tile exclusive scan (coalesced) ----------------
__global__ __launch_bounds__(1024) void kB1_tile_scan(
    const unsigned* __restrict__ deg, unsigned* __restrict__ offs,
    unsigned* __restrict__ tilesum, int N)
{
    __shared__ unsigned lds[TILE];
    __shared__ unsigned sums[1024];
    const int t = threadIdx.x;
    const int base = blockIdx.x << TILE_LOG;
    #pragma unroll
    for (int i = 0; i < 4; ++i) {
        const int idx = base + t + i * 1024;
        lds[t + i * 1024] = (idx < N) ? deg[idx] : 0u;   // coalesced
    }
    __syncthreads();
    unsigned s = lds[4 * t] + lds[4 * t + 1] + lds[4 * t + 2] + lds[4 * t + 3];
    sums[t] = s;
    __syncthreads();
    for (int off = 1; off < 1024; off <<= 1) {
        const unsigned v = (t >= off) ? sums[t - off] : 0u;
        __syncthreads();
        sums[t] += v;
        __syncthreads();
    }
    unsigned run = sums[t] - s;
    #pragma unroll
    for (int i = 0; i < 4; ++i) {
        const unsigned tmp = lds[4 * t + i];
        lds[4 * t + i] = run;
        run += tmp;
    }
    __syncthreads();
    #pragma unroll
    for (int i = 0; i < 4; ++i) {
        const int idx = base + t + i * 1024;
        if (idx < N) offs[idx] = lds[t + i * 1024];      // coalesced
    }
    if (t == 1023) tilesum[blockIdx.x] = sums[1023];
}

// ---------------- kB2: scan tile totals ----------------
__global__ void kB2_scan_tiles(
    const unsigned* __restrict__ tilesum, unsigned* __restrict__ tileoff,
    unsigned* __restrict__ offs, int ntiles, int N)
{
    if (threadIdx.x == 0 && blockIdx.x == 0) {
        unsigned run = 0;
        for (int b = 0; b < ntiles; ++b) { tileoff[b] = run; run += tilesum[b]; }
        offs[N] = run;   // == E
    }
}

// ---------------- kB3: globalize offsets, emit cursor ----------------
__global__ __launch_bounds__(256) void kB3_add_offs(
    unsigned* __restrict__ offs, unsigned* __restrict__ cursor,
    const unsigned* __restrict__ tileoff, int N)
{
    const long long stride = (long long)gridDim.x * blockDim.x;
    for (long long i = (long long)blockIdx.x * blockDim.x + threadIdx.x; i < N; i += stride) {
        const unsigned o = offs[i] + tileoff[i >> TILE_LOG];
        offs[i] = o;
        cursor[i] = o;
    }
}

// ---------------- kC1: PURE gate stream ----------------
// Each wave: 16 consecutive edges/iter as 4 quads; the 4 rv loads are
// independent (4KB in flight/wave). scale writes: lanes 0,16,32,48 write
// 4 consecutive floats per quad -> 64B contiguous per wave-iter.
__global__ __launch_bounds__(256) void kC1_gate(
    const float* __restrict__ review_feat,  // [E,64]
    const float* __restrict__ ps_w,         // [64]
    float*       __restrict__ scale,        // [E] out: sigmoid(dot)
    int E)
{
    const int lane  = threadIdx.x & 63;
    const int wib   = threadIdx.x >> 6;
    const int group = lane >> 4;
    const int sub   = lane & 15;
    const float4 pw = *reinterpret_cast<const float4*>(ps_w + sub * 4);

    const long long nwaves = (long long)gridDim.x * 4;
    for (long long w = (long long)blockIdx.x * 4 + wib; w * 16 < E; w += nwaves) {
        const long long ebase = w * 16;
        float4 rv[4];
        #pragma unroll
        for (int u = 0; u < 4; ++u) {
            const long long e = ebase + u * 4 + group;
            rv[u] = (e < E) ? *reinterpret_cast<const float4*>(review_feat + e * 64 + sub * 4)
                            : make_float4(0.f, 0.f, 0.f, 0.f);
        }
        float x[4];
        #pragma unroll
        for (int u = 0; u < 4; ++u) {
            float t = rv[u].x * pw.x + rv[u].y * pw.y + rv[u].z * pw.z + rv[u].w * pw.w;
            t += __shfl_xor(t, 1);
            t += __shfl_xor(t, 2);
            t += __shfl_xor(t, 4);
            t += __shfl_xor(t, 8);
            x[u] = t;
        }
        if (sub == 0) {
            #pragma unroll
            for (int u = 0; u < 4; ++u) {
                const long long e = ebase + u * 4 + group;
                if (e < E) scale[e] = 1.f / (1.f + __expf(-x[u]));
            }
        }
    }
}

// ---------------- kC2: CSR scatter, one thread per edge ----------------
__global__ __launch_bounds__(256) void kC2_scatter(
    const int*   __restrict__ src,
    const int*   __restrict__ dst,
    const float* __restrict__ scale,
    const float* __restrict__ cj,
    const float* __restrict__ ci,
    unsigned*    __restrict__ cursor,
    int2*        __restrict__ pairs,
    int E)
{
    const long long e = (long long)blockIdx.x * 256 + threadIdx.x;
    if (e >= E) return;
    const int s = src[e];
    const int d = dst[e];
    const float sc = scale[e] * cj[s] * ci[d];   // fold cj*ci here
    const unsigned pos = atomicAdd(&cursor[d], 1u);
    pairs[pos] = make_int2(s, __float_as_int(sc));
}

// ---------------- kD: gather-reduce (round-6 version, unchanged) ----------------
__global__ __launch_bounds__(256, 4) void kD_gather(
    const float* __restrict__ weight, const unsigned* __restrict__ offs,
    const int2* __restrict__ pairs, float* __restrict__ out, int N)
{
    const int lane  = threadIdx.x & 63;
    const int wib   = threadIdx.x >> 6;
    const int group = lane >> 4;   // node within wave
    const int sub   = lane & 15;   // float4 chunk of the row

    const long long n = ((long long)blockIdx.x * 4 + wib) * 4 + group;
    const bool valid = (n < N);

    unsigned start = 0, cnt = 0;
    if (valid) { start = offs[n]; cnt = offs[n + 1] - start; }

    int2 p = make_int2(0, 0);
    if (sub < cnt) p = pairs[start + sub];

    float4 acc = make_float4(0.f, 0.f, 0.f, 0.f);
    for (unsigned k0 = 0; __any((int)(k0 < cnt)); k0 += 16) {
        int2 pn = make_int2(0, 0);
        const unsigned nk = k0 + 16;
        if (nk + sub < cnt) pn = pairs[start + nk + sub];

        int m = (int)cnt - (int)k0;
        if (m > 16) m = 16;
        #pragma unroll 8
        for (int j = 0; j < m; ++j) {
            const int   s  = __shfl(p.x, (group << 4) + j);
            const float sc = __int_as_float(__shfl(p.y, (group << 4) + j));
            const float4 w = *reinterpret_cast<const float4*>(
                weight + (long long)s * 64 + sub * 4);
            acc.x += sc * w.x;
            acc.y += sc * w.y;
            acc.z += sc * w.z;
            acc.w += sc * w.w;
        }
        p = pn;
    }
    if (valid)
        *reinterpret_cast<float4*>(out + n * 64 + sub * 4) = acc;
}

extern "C" void kernel_launch(void* const* d_in, const int* in_sizes, int n_in,
                              void* d_out, int out_size, void* d_ws, size_t ws_size,
                              hipStream_t stream) {
    const float* weight      = (const float*)d_in[0];
    const float* ps_w        = (const float*)d_in[1];
    const float* review_feat = (const float*)d_in[2];
    const float* cj          = (const float*)d_in[3];
    const float* ci          = (const float*)d_in[4];
    const int*   src         = (const int*)d_in[5];
    const int*   dst         = (const int*)d_in[6];
    float*       out         = (float*)d_out;

    const int N = in_sizes[3];
    const int E = in_sizes[5];
    const int ntiles = (N + TILE - 1) / TILE;

    size_t off = 0;
    auto take = [&](size_t bytes) { size_t o = off; off = (off + bytes + 255) & ~(size_t)255; return o; };
    const size_t pairs_o   = take((size_t)E * 8);
    const size_t scale_o   = take((size_t)E * 4);
    const size_t deg_o     = take((size_t)N * 4);
    const size_t offs_o    = take(((size_t)N + 1) * 4);
    const size_t cursor_o  = take((size_t)N * 4);
    const size_t tilesum_o = take((size_t)ntiles * 4);
    const size_t tileoff_o = take((size_t)ntiles * 4);

    char* base = (char*)d_ws;
    int2*     pairs   = (int2*)    (base + pairs_o);
    float*    scale   = (float*)   (base + scale_o);
    unsigned* deg     = (unsigned*)(base + deg_o);
    unsigned* offs    = (unsigned*)(base + offs_o);
    unsigned* cursor  = (unsigned*)(base + cursor_o);
    unsigned* tilesum = (unsigned*)(base + tilesum_o);
    unsigned* tileoff = (unsigned*)(base + tileoff_o);

    kZ_zero<<<(N + 255) / 256, 256, 0, stream>>>(deg, N);
    kA_hist<<<2048, 256, 0, stream>>>(dst, deg, E);
    kB1_tile_scan<<<ntiles, 1024, 0, stream>>>(deg, offs, tilesum, N);
    kB2_scan_tiles<<<1, 64, 0, stream>>>(tilesum, tileoff, offs, ntiles, N);
    kB3_add_offs<<<256, 256, 0, stream>>>(offs, cursor, tileoff, N);
    kC1_gate<<<2048, 256, 0, stream>>>(review_feat, ps_w, scale, E);
    kC2_scatter<<<(E + 255) / 256, 256, 0, stream>>>(src, dst, scale, cj, ci,
                                                     cursor, pairs, E);
    const int blocksD = (N + 15) / 16;   // 16 nodes per block (4 waves x 4 nodes)
    kD_gather<<<blocksD, 256, 0, stream>>>(weight, offs, pairs, out, N);
}